// Round 4
// baseline (419.576 us; speedup 1.0000x reference)
//
#include <hip/hip_runtime.h>
#include <hip/hip_bf16.h>

// RMSNorm + dynamic per-token int8 quant.
// x: [R=16384, H=4096] fp32, w: [H] fp32.
// out: first R*H floats = quantized values (as fp32), next R floats = scales.
//
// q = round(x*w * 127 / max|x*w|) -- rstd cancels; single pass, row resident
// in registers.
// R4: wave-per-row. One 64-lane wave owns a whole row (16 fx4/lane of x*w),
// no LDS, no __syncthreads -- each wave is an independent load->reduce->store
// pipeline, so read/write streams interleave at the finest grain and the
// reduction is a pure 6-step shuffle. x loads + q stores are nontemporal
// (537 MB streamed once); w loads stay cached (reused by all 16384 waves).

constexpr int H = 4096;
constexpr int WAVE = 64;
constexpr int VPT = H / (WAVE * 4); // 16 fx4 per lane

typedef float fx4 __attribute__((ext_vector_type(4)));

__global__ __launch_bounds__(WAVE)
void qrmsnorm_kernel(const float* __restrict__ x, const float* __restrict__ w,
                     float* __restrict__ out, float* __restrict__ scale_out) {
    const int row = blockIdx.x;
    const fx4* __restrict__ xv = (const fx4*)(x + (long long)row * H);
    const fx4* __restrict__ wv = (const fx4*)w;

    fx4 p[VPT];
    float ss = 0.0f, am = 0.0f;

#pragma unroll
    for (int j = 0; j < VPT; ++j) {
        const int idx = j * WAVE + threadIdx.x;    // coalesced, 16B/lane
        fx4 a = __builtin_nontemporal_load(&xv[idx]);
        fx4 c = wv[idx];                           // cached (chip-wide reuse)
        ss = fmaf(a.x, a.x, ss); ss = fmaf(a.y, a.y, ss);
        ss = fmaf(a.z, a.z, ss); ss = fmaf(a.w, a.w, ss);
        a *= c;
        am = fmaxf(am, fmaxf(fmaxf(fabsf(a.x), fabsf(a.y)),
                             fmaxf(fabsf(a.z), fabsf(a.w))));
        p[j] = a;
    }

    // wave(64) butterfly reduction -- no LDS, no barrier
#pragma unroll
    for (int off = 32; off > 0; off >>= 1) {
        ss += __shfl_xor(ss, off);
        am = fmaxf(am, __shfl_xor(am, off));
    }

    const float inv = (am > 0.0f) ? (127.0f / am) : 0.0f;

    fx4* __restrict__ ov = (fx4*)(out + (long long)row * H);
#pragma unroll
    for (int j = 0; j < VPT; ++j) {
        const int idx = j * WAVE + threadIdx.x;
        fx4 a = p[j], q;
        q.x = fminf(fmaxf(rintf(a.x * inv), -128.0f), 127.0f);
        q.y = fminf(fmaxf(rintf(a.y * inv), -128.0f), 127.0f);
        q.z = fminf(fmaxf(rintf(a.z * inv), -128.0f), 127.0f);
        q.w = fminf(fmaxf(rintf(a.w * inv), -128.0f), 127.0f);
        __builtin_nontemporal_store(q, &ov[idx]);
    }

    if (threadIdx.x == 0) {
        const float rstd = rsqrtf(ss * (1.0f / (float)H) + 1e-6f);
        scale_out[row] = am * rstd * (1.0f / 127.0f);
    }
}

extern "C" void kernel_launch(void* const* d_in, const int* in_sizes, int n_in,
                              void* d_out, int out_size, void* d_ws, size_t ws_size,
                              hipStream_t stream) {
    const float* x = (const float*)d_in[0];
    const float* w = (const float*)d_in[1];
    float* out = (float*)d_out;

    const int h = in_sizes[1];            // 4096
    const int rows = in_sizes[0] / h;     // 16384
    float* scale_out = out + (long long)rows * h;

    qrmsnorm_kernel<<<rows, WAVE, 0, stream>>>(x, w, out, scale_out);
}